// Round 1
// baseline (2626.251 us; speedup 1.0000x reference)
//
#include <hip/hip_runtime.h>
#include <stdint.h>

// 1 = JAX >= 0.5 default (jax_threefry_partitionable=True); 0 = legacy scheme.
#define JAX_PARTITIONABLE 1

constexpr int kC = 64;          // channels (= NMF rows T)
constexpr int kS = 65536;       // spatial 16*64*64 (= NMF cols M)
constexpr int kL = 8;           // NMF rank
constexpr int kIters = 50;
constexpr int kBlocks = 256;
constexpr int kThreads = 256;
constexpr int kGroups = 16;     // stage-1 reduction groups (16 blocks/group)
constexpr int kEntries = 576;   // 512 (VH^T) + 64 (HH^T)
constexpr float kEps = 1.1920929e-07f;

struct Ctl {
  unsigned bar_cnt; unsigned pad0[15];
  unsigned bar_gen; unsigned pad1[15];
  float mean_sum; float err_sum; float pad2[14];
  float B[3][kGroups][kEntries];   // rotating accumulator buffers
};

__device__ __forceinline__ uint2 tf2x32(unsigned k0, unsigned k1,
                                        unsigned x0, unsigned x1) {
  unsigned k2 = k0 ^ k1 ^ 0x1BD11BDAu;
  x0 += k0; x1 += k1;
#define TF_RND(r) { x0 += x1; x1 = (x1 << (r)) | (x1 >> (32 - (r))); x1 ^= x0; }
  TF_RND(13) TF_RND(15) TF_RND(26) TF_RND(6)
  x0 += k1; x1 += k2 + 1u;
  TF_RND(17) TF_RND(29) TF_RND(16) TF_RND(24)
  x0 += k2; x1 += k0 + 2u;
  TF_RND(13) TF_RND(15) TF_RND(26) TF_RND(6)
  x0 += k0; x1 += k1 + 3u;
  TF_RND(17) TF_RND(29) TF_RND(16) TF_RND(24)
  x0 += k1; x1 += k2 + 4u;
  TF_RND(13) TF_RND(15) TF_RND(26) TF_RND(6)
  x0 += k2; x1 += k0 + 5u;
#undef TF_RND
  return make_uint2(x0, x1);
}

__device__ __forceinline__ float u01(unsigned b) {
  return __uint_as_float((b >> 9) | 0x3f800000u) - 1.0f;
}

// Hand-rolled grid barrier (all kBlocks are guaranteed co-resident:
// 256 blocks / 256 CUs, <=2 blocks/CU always fit with our LDS+VGPR budget).
__device__ __forceinline__ void gridbar(Ctl* ctl) {
  __threadfence();
  __syncthreads();
  if (threadIdx.x == 0) {
    unsigned g = __hip_atomic_load(&ctl->bar_gen, __ATOMIC_RELAXED, __HIP_MEMORY_SCOPE_AGENT);
    unsigned a = __hip_atomic_fetch_add(&ctl->bar_cnt, 1u, __ATOMIC_ACQ_REL, __HIP_MEMORY_SCOPE_AGENT);
    if (a == kBlocks - 1) {
      __hip_atomic_store(&ctl->bar_cnt, 0u, __ATOMIC_RELAXED, __HIP_MEMORY_SCOPE_AGENT);
      __hip_atomic_fetch_add(&ctl->bar_gen, 1u, __ATOMIC_RELEASE, __HIP_MEMORY_SCOPE_AGENT);
    } else {
      while (__hip_atomic_load(&ctl->bar_gen, __ATOMIC_RELAXED, __HIP_MEMORY_SCOPE_AGENT) == g)
        __builtin_amdgcn_s_sleep(2);
    }
  }
  __syncthreads();
  __threadfence();
}

__global__ void init_ctl(unsigned* ws) {
  const unsigned n = (unsigned)(sizeof(Ctl) / 4);
  for (unsigned i = blockIdx.x * blockDim.x + threadIdx.x; i < n;
       i += gridDim.x * blockDim.x)
    ws[i] = 0u;
}

__global__ __launch_bounds__(kThreads, 2) void fsam_nmf(
    const float* __restrict__ eps, const float* __restrict__ w_pre,
    const float* __restrict__ b_pre, const float* __restrict__ w_post1,
    const float* __restrict__ w_post2, float* __restrict__ out, Ctl* ctl) {
  // Padded to 260: stride%32==4 -> conflict-free for both stride-1 reads and
  // the 8-distinct-row float4 GEMM reads; rows stay 16B aligned.
  __shared__ __align__(16) float Vs[kC][260];
  __shared__ __align__(16) float Hs[kL][260];
  __shared__ __align__(16) float Ws[kC][kL];
  __shared__ __align__(16) float WtWs[kL * kL];
  __shared__ __align__(16) float hhts[kL * kL];
  __shared__ float reds[4];

  const int tid = threadIdx.x;
  const int s = blockIdx.x * kThreads + tid;  // this thread's spatial column

  // ---------------- phase 0: V column = relu(W_pre . eps_col + b) ----------
  float acc[kC];
#pragma unroll
  for (int o = 0; o < kC; ++o) acc[o] = b_pre[o];
  for (int c = 0; c < kC; ++c) {
    float e = eps[c * kS + s];
#pragma unroll
    for (int o = 0; o < kC; ++o) acc[o] = fmaf(w_pre[o * kC + c], e, acc[o]);
  }
  float lsum = 0.0f;
#pragma unroll
  for (int o = 0; o < kC; ++o) {
    acc[o] = fmaxf(acc[o], 0.0f);
    Vs[o][tid] = acc[o];
    lsum += acc[o];
  }
  // block-reduce lsum -> atomicAdd
  {
    float r = lsum;
#pragma unroll
    for (int off = 32; off > 0; off >>= 1) r += __shfl_down(r, off, 64);
    if ((tid & 63) == 0) reds[tid >> 6] = r;
    __syncthreads();
    if (tid == 0) atomicAdd(&ctl->mean_sum, reds[0] + reds[1] + reds[2] + reds[3]);
  }
  gridbar(ctl);
  const float avg = sqrtf(ctl->mean_sum * (1.0f / (4194304.0f * 8.0f)));

  // ---------------- threefry init (JAX-exact) -------------------------------
#if JAX_PARTITIONABLE
  const uint2 kw = tf2x32(0u, 0u, 0u, 0u);  // split foldlike: key_i = tf(key,(0,i))
  const uint2 kh = tf2x32(0u, 0u, 0u, 1u);
#else
  const uint2 A0 = tf2x32(0u, 0u, 0u, 2u);  // original split: counts [0,1]|[2,3]
  const uint2 A1 = tf2x32(0u, 0u, 1u, 3u);
  const uint2 kw = make_uint2(A0.x, A1.x);
  const uint2 kh = make_uint2(A0.y, A1.y);
#endif

  float h[kL];
#if JAX_PARTITIONABLE
#pragma unroll
  for (int l = 0; l < kL; ++l) {
    uint2 r = tf2x32(kh.x, kh.y, 0u, (unsigned)(l * kS + s));
    h[l] = avg * u01(r.x ^ r.y);
  }
#else
#pragma unroll
  for (int l = 0; l < 4; ++l) {
    unsigned i = (unsigned)(l * kS + s);
    uint2 r = tf2x32(kh.x, kh.y, i, i + 262144u);
    h[l] = avg * u01(r.x);
    h[l + 4] = avg * u01(r.y);
  }
#endif
  // W0 (each block redundantly; flat index i = c*8+l)
  {
#if JAX_PARTITIONABLE
    uint2 r0 = tf2x32(kw.x, kw.y, 0u, (unsigned)tid);
    uint2 r1 = tf2x32(kw.x, kw.y, 0u, (unsigned)(tid + 256));
    (&Ws[0][0])[tid] = avg * u01(r0.x ^ r0.y);
    (&Ws[0][0])[tid + 256] = avg * u01(r1.x ^ r1.y);
#else
    uint2 r = tf2x32(kw.x, kw.y, (unsigned)tid, (unsigned)(tid + 256));
    (&Ws[0][0])[tid] = avg * u01(r.x);
    (&Ws[0][0])[tid + 256] = avg * u01(r.y);
#endif
  }
  __syncthreads();
  if (tid < kL * kL) {
    const int l = tid >> 3, j = tid & 7;
    float sum = 0.0f;
    for (int c = 0; c < kC; ++c) sum = fmaf(Ws[c][l], Ws[c][j], sum);
    WtWs[tid] = sum;
  }
  __syncthreads();

  // ---------------- 50 MU iterations, one grid barrier each -----------------
  for (int it = 0; it < kIters; ++it) {
    // H update: h *= (W^T V)_col / ((W^T W) h + eps)   [old W]
    float num[kL] = {0, 0, 0, 0, 0, 0, 0, 0};
    for (int c = 0; c < kC; ++c) {
      const float v = Vs[c][tid];
      const float4 w0 = *(const float4*)&Ws[c][0];
      const float4 w1 = *(const float4*)&Ws[c][4];
      num[0] = fmaf(v, w0.x, num[0]); num[1] = fmaf(v, w0.y, num[1]);
      num[2] = fmaf(v, w0.z, num[2]); num[3] = fmaf(v, w0.w, num[3]);
      num[4] = fmaf(v, w1.x, num[4]); num[5] = fmaf(v, w1.y, num[5]);
      num[6] = fmaf(v, w1.z, num[6]); num[7] = fmaf(v, w1.w, num[7]);
    }
    float hn[kL];
#pragma unroll
    for (int l = 0; l < kL; ++l) {
      const float4 a = *(const float4*)&WtWs[l * kL];
      const float4 b = *(const float4*)&WtWs[l * kL + 4];
      float d = kEps;
      d = fmaf(a.x, h[0], d); d = fmaf(a.y, h[1], d);
      d = fmaf(a.z, h[2], d); d = fmaf(a.w, h[3], d);
      d = fmaf(b.x, h[4], d); d = fmaf(b.y, h[5], d);
      d = fmaf(b.z, h[6], d); d = fmaf(b.w, h[7], d);
      hn[l] = h[l] * num[l] / d;
    }
#pragma unroll
    for (int l = 0; l < kL; ++l) { h[l] = hn[l]; Hs[l][tid] = hn[l]; }

    // block 0 pre-zeroes the buffer for iteration it+1 (3-buffer rotation
    // makes this safe with a single barrier per iteration)
    if (blockIdx.x == 0) {
      float* nb = &ctl->B[(it + 1) % 3][0][0];
      for (int k = tid; k < kGroups * kEntries; k += kThreads)
        __hip_atomic_store(&nb[k], 0.0f, __ATOMIC_RELAXED, __HIP_MEMORY_SCOPE_AGENT);
    }
    __syncthreads();

    // block-local partial VH^T and HH^T over this block's 256 columns
    float* Bg = &ctl->B[it % 3][blockIdx.x & (kGroups - 1)][0];
    {
      const int c0 = tid >> 3, l = tid & 7;
      float a0 = 0.0f, a1 = 0.0f;
      for (int s4 = 0; s4 < kThreads; s4 += 4) {
        const float4 hv = *(const float4*)&Hs[l][s4];
        const float4 v0 = *(const float4*)&Vs[c0][s4];
        const float4 v1 = *(const float4*)&Vs[c0 + 32][s4];
        a0 = fmaf(v0.x, hv.x, a0); a0 = fmaf(v0.y, hv.y, a0);
        a0 = fmaf(v0.z, hv.z, a0); a0 = fmaf(v0.w, hv.w, a0);
        a1 = fmaf(v1.x, hv.x, a1); a1 = fmaf(v1.y, hv.y, a1);
        a1 = fmaf(v1.z, hv.z, a1); a1 = fmaf(v1.w, hv.w, a1);
      }
      atomicAdd(&Bg[tid], a0);          // entry (c0,l) == flat tid
      atomicAdd(&Bg[tid + 256], a1);    // entry (c0+32,l)
    }
    if (tid < kL * kL) {
      const int j = tid >> 3, l2 = tid & 7;
      float a = 0.0f;
      for (int s4 = 0; s4 < kThreads; s4 += 4) {
        const float4 x = *(const float4*)&Hs[j][s4];
        const float4 y = *(const float4*)&Hs[l2][s4];
        a = fmaf(x.x, y.x, a); a = fmaf(x.y, y.y, a);
        a = fmaf(x.z, y.z, a); a = fmaf(x.w, y.w, a);
      }
      atomicAdd(&Bg[512 + tid], a);
    }

    gridbar(ctl);

    // finalize 16-group sums; every block redundantly recomputes W and W^T W
    const float* Bb = &ctl->B[it % 3][0][0];
    if (tid < kL * kL) {
      float sum = 0.0f;
#pragma unroll
      for (int g = 0; g < kGroups; ++g) sum += Bb[g * kEntries + 512 + tid];
      hhts[tid] = sum;
    }
    __syncthreads();
    float wn0, wn1;
    {
      float v0 = 0.0f, v1 = 0.0f;
#pragma unroll
      for (int g = 0; g < kGroups; ++g) {
        v0 += Bb[g * kEntries + tid];
        v1 += Bb[g * kEntries + tid + 256];
      }
      const int c0 = tid >> 3, l0 = tid & 7;
      float d0 = kEps, d1 = kEps;
#pragma unroll
      for (int j = 0; j < kL; ++j) {
        const float hh = hhts[j * kL + l0];
        d0 = fmaf(Ws[c0][j], hh, d0);
        d1 = fmaf(Ws[c0 + 32][j], hh, d1);
      }
      wn0 = Ws[c0][l0] * v0 / d0;
      wn1 = Ws[c0 + 32][l0] * v1 / d1;
    }
    __syncthreads();
    (&Ws[0][0])[tid] = wn0;
    (&Ws[0][0])[tid + 256] = wn1;
    __syncthreads();
    if (tid < kL * kL) {
      const int l = tid >> 3, j = tid & 7;
      float sum = 0.0f;
      for (int c = 0; c < kC; ++c) sum = fmaf(Ws[c][l], Ws[c][j], sum);
      WtWs[tid] = sum;
    }
    __syncthreads();
  }

  // ---------------- epilogue ------------------------------------------------
  // Vhat column + Frobenius error contribution
  float vh[kC];
  float errp = 0.0f;
#pragma unroll
  for (int c = 0; c < kC; ++c) {
    const float4 w0 = *(const float4*)&Ws[c][0];
    const float4 w1 = *(const float4*)&Ws[c][4];
    float t = 0.0f;
    t = fmaf(w0.x, h[0], t); t = fmaf(w0.y, h[1], t);
    t = fmaf(w0.z, h[2], t); t = fmaf(w0.w, h[3], t);
    t = fmaf(w1.x, h[4], t); t = fmaf(w1.y, h[5], t);
    t = fmaf(w1.z, h[6], t); t = fmaf(w1.w, h[7], t);
    vh[c] = t;
    const float d = Vs[c][tid] - t;
    errp = fmaf(d, d, errp);
  }
  {
    float r = errp;
#pragma unroll
    for (int off = 32; off > 0; off >>= 1) r += __shfl_down(r, off, 64);
    __syncthreads();
    if ((tid & 63) == 0) reds[tid >> 6] = r;
    __syncthreads();
    if (tid == 0) atomicAdd(&ctl->err_sum, reds[0] + reds[1] + reds[2] + reds[3]);
  }
  // eps_hat = w_post2 . relu(w_post1 . vh), streamed so only vh+outacc live
  float outacc[kC];
#pragma unroll
  for (int o = 0; o < kC; ++o) outacc[o] = 0.0f;
  for (int o = 0; o < kC; ++o) {
    float t = 0.0f;
#pragma unroll
    for (int c = 0; c < kC; ++c) t = fmaf(w_post1[o * kC + c], vh[c], t);
    t = fmaxf(t, 0.0f);
#pragma unroll
    for (int o2 = 0; o2 < kC; ++o2)
      outacc[o2] = fmaf(w_post2[o2 * kC + o], t, outacc[o2]);
  }
#pragma unroll
  for (int o = 0; o < kC; ++o) out[o * kS + s] = outacc[o];

  gridbar(ctl);
  if (blockIdx.x == 0 && tid == 0) out[kC * kS] = sqrtf(ctl->err_sum);
}

extern "C" void kernel_launch(void* const* d_in, const int* in_sizes, int n_in,
                              void* d_out, int out_size, void* d_ws, size_t ws_size,
                              hipStream_t stream) {
  (void)in_sizes; (void)n_in; (void)out_size; (void)ws_size;
  const float* eps     = (const float*)d_in[0];
  const float* w_pre   = (const float*)d_in[1];
  const float* b_pre   = (const float*)d_in[2];
  const float* w_post1 = (const float*)d_in[3];
  const float* w_post2 = (const float*)d_in[4];
  float* out = (float*)d_out;
  Ctl* ctl = (Ctl*)d_ws;

  init_ctl<<<64, 256, 0, stream>>>((unsigned*)d_ws);
  fsam_nmf<<<kBlocks, kThreads, 0, stream>>>(eps, w_pre, b_pre, w_post1,
                                             w_post2, out, ctl);
}

// Round 2
// 918.010 us; speedup vs baseline: 2.8608x; 2.8608x over previous
//
#include <hip/hip_runtime.h>
#include <stdint.h>

// 1 = JAX >= 0.5 default (jax_threefry_partitionable=True); 0 = legacy scheme.
#define JAX_PARTITIONABLE 1

constexpr int kC = 64;          // channels (= NMF rows T)
constexpr int kS = 65536;       // spatial 16*64*64 (= NMF cols M)
constexpr int kL = 8;           // NMF rank
constexpr int kIters = 50;
constexpr int kBlocks = 256;
constexpr int kThreads = 256;
constexpr int kGroups = 16;     // stage-1 reduction groups (16 blocks/group)
constexpr int kEntries = 576;   // 512 (VH^T) + 64 (HH^T)
constexpr float kEps = 1.1920929e-07f;

#define AGENT __HIP_MEMORY_SCOPE_AGENT

struct Ctl {
  unsigned bar_cnt; unsigned pad0[15];   // monotonic arrival counter
  float mean_sum; float err_sum; float pad2[14];
  float B[3][kGroups][kEntries];         // rotating accumulator buffers
};

__device__ __forceinline__ uint2 tf2x32(unsigned k0, unsigned k1,
                                        unsigned x0, unsigned x1) {
  unsigned k2 = k0 ^ k1 ^ 0x1BD11BDAu;
  x0 += k0; x1 += k1;
#define TF_RND(r) { x0 += x1; x1 = (x1 << (r)) | (x1 >> (32 - (r))); x1 ^= x0; }
  TF_RND(13) TF_RND(15) TF_RND(26) TF_RND(6)
  x0 += k1; x1 += k2 + 1u;
  TF_RND(17) TF_RND(29) TF_RND(16) TF_RND(24)
  x0 += k2; x1 += k0 + 2u;
  TF_RND(13) TF_RND(15) TF_RND(26) TF_RND(6)
  x0 += k0; x1 += k1 + 3u;
  TF_RND(17) TF_RND(29) TF_RND(16) TF_RND(24)
  x0 += k1; x1 += k2 + 4u;
  TF_RND(13) TF_RND(15) TF_RND(26) TF_RND(6)
  x0 += k2; x1 += k0 + 5u;
#undef TF_RND
  return make_uint2(x0, x1);
}

__device__ __forceinline__ float u01(unsigned b) {
  return __uint_as_float((b >> 9) | 0x3f800000u) - 1.0f;
}

// Monotonic grid barrier: one relaxed RMW per block + one acquire fence.
// Safety: __syncthreads drains each wave's vmcnt (compiler-emitted s_waitcnt
// before s_barrier), so every sc1-flagged cross-block op is at the coherence
// point (L3) before the arrival add is issued. cnt >= round*kBlocks therefore
// implies all blocks' data ops for this round are globally visible. The single
// acquire fence (buffer_inv sc1) makes subsequent NORMAL loads refetch L1/L2.
__device__ __forceinline__ void gridbar(Ctl* ctl, unsigned& round) {
  ++round;
  __syncthreads();
  if (threadIdx.x == 0) {
    const unsigned target = round * (unsigned)kBlocks;
    unsigned a = __hip_atomic_fetch_add(&ctl->bar_cnt, 1u, __ATOMIC_RELAXED, AGENT);
    if (a != target - 1u) {
      while (__hip_atomic_load(&ctl->bar_cnt, __ATOMIC_RELAXED, AGENT) < target)
        __builtin_amdgcn_s_sleep(1);
    }
    __builtin_amdgcn_fence(__ATOMIC_ACQUIRE, "agent");
  }
  __syncthreads();
}

__global__ void init_ctl(unsigned* ws) {
  const unsigned n = (unsigned)(sizeof(Ctl) / 4);
  for (unsigned i = blockIdx.x * blockDim.x + threadIdx.x; i < n;
       i += gridDim.x * blockDim.x)
    ws[i] = 0u;
}

__global__ __launch_bounds__(kThreads, 2) void fsam_nmf(
    const float* __restrict__ eps, const float* __restrict__ w_pre,
    const float* __restrict__ b_pre, const float* __restrict__ w_post1,
    const float* __restrict__ w_post2, float* __restrict__ out, Ctl* ctl) {
  // Padded to 260: stride%32==4 -> conflict-free for both stride-1 reads and
  // the 8-distinct-row float4 GEMM reads; rows stay 16B aligned.
  __shared__ __align__(16) float Vs[kC][260];
  __shared__ __align__(16) float Hs[kL][260];
  __shared__ __align__(16) float Ws[kC][kL];
  __shared__ __align__(16) float WtWs[kL * kL];
  __shared__ __align__(16) float hhts[kL * kL];
  __shared__ float reds[4];

  const int tid = threadIdx.x;
  const int s = blockIdx.x * kThreads + tid;  // this thread's spatial column
  unsigned bar_round = 0;

  // ---------------- phase 0: V column = relu(W_pre . eps_col + b) ----------
  float acc[kC];
#pragma unroll
  for (int o = 0; o < kC; ++o) acc[o] = b_pre[o];
  for (int c = 0; c < kC; ++c) {
    float e = eps[c * kS + s];
#pragma unroll
    for (int o = 0; o < kC; ++o) acc[o] = fmaf(w_pre[o * kC + c], e, acc[o]);
  }
  float lsum = 0.0f;
#pragma unroll
  for (int o = 0; o < kC; ++o) {
    acc[o] = fmaxf(acc[o], 0.0f);
    Vs[o][tid] = acc[o];
    lsum += acc[o];
  }
  // block-reduce lsum -> one device-scope atomicAdd
  {
    float r = lsum;
#pragma unroll
    for (int off = 32; off > 0; off >>= 1) r += __shfl_down(r, off, 64);
    if ((tid & 63) == 0) reds[tid >> 6] = r;
    __syncthreads();
    if (tid == 0)
      __hip_atomic_fetch_add(&ctl->mean_sum, reds[0] + reds[1] + reds[2] + reds[3],
                             __ATOMIC_RELAXED, AGENT);
  }
  gridbar(ctl, bar_round);
  const float avg = sqrtf(
      __hip_atomic_load(&ctl->mean_sum, __ATOMIC_RELAXED, AGENT) *
      (1.0f / (4194304.0f * 8.0f)));

  // ---------------- threefry init (JAX-exact) -------------------------------
#if JAX_PARTITIONABLE
  const uint2 kw = tf2x32(0u, 0u, 0u, 0u);  // split foldlike: key_i = tf(key,(0,i))
  const uint2 kh = tf2x32(0u, 0u, 0u, 1u);
#else
  const uint2 A0 = tf2x32(0u, 0u, 0u, 2u);  // original split: counts [0,1]|[2,3]
  const uint2 A1 = tf2x32(0u, 0u, 1u, 3u);
  const uint2 kw = make_uint2(A0.x, A1.x);
  const uint2 kh = make_uint2(A0.y, A1.y);
#endif

  float h[kL];
#if JAX_PARTITIONABLE
#pragma unroll
  for (int l = 0; l < kL; ++l) {
    uint2 r = tf2x32(kh.x, kh.y, 0u, (unsigned)(l * kS + s));
    h[l] = avg * u01(r.x ^ r.y);
  }
#else
#pragma unroll
  for (int l = 0; l < 4; ++l) {
    unsigned i = (unsigned)(l * kS + s);
    uint2 r = tf2x32(kh.x, kh.y, i, i + 262144u);
    h[l] = avg * u01(r.x);
    h[l + 4] = avg * u01(r.y);
  }
#endif
  // W0 (each block redundantly; flat index i = c*8+l)
  {
#if JAX_PARTITIONABLE
    uint2 r0 = tf2x32(kw.x, kw.y, 0u, (unsigned)tid);
    uint2 r1 = tf2x32(kw.x, kw.y, 0u, (unsigned)(tid + 256));
    (&Ws[0][0])[tid] = avg * u01(r0.x ^ r0.y);
    (&Ws[0][0])[tid + 256] = avg * u01(r1.x ^ r1.y);
#else
    uint2 r = tf2x32(kw.x, kw.y, (unsigned)tid, (unsigned)(tid + 256));
    (&Ws[0][0])[tid] = avg * u01(r.x);
    (&Ws[0][0])[tid + 256] = avg * u01(r.y);
#endif
  }
  __syncthreads();
  if (tid < kL * kL) {
    const int l = tid >> 3, j = tid & 7;
    float sum = 0.0f;
    for (int c = 0; c < kC; ++c) sum = fmaf(Ws[c][l], Ws[c][j], sum);
    WtWs[tid] = sum;
  }
  __syncthreads();

  // ---------------- 50 MU iterations, one grid barrier each -----------------
  for (int it = 0; it < kIters; ++it) {
    // H update: h *= (W^T V)_col / ((W^T W) h + eps)   [old W]
    float num[kL] = {0, 0, 0, 0, 0, 0, 0, 0};
    for (int c = 0; c < kC; ++c) {
      const float v = Vs[c][tid];
      const float4 w0 = *(const float4*)&Ws[c][0];
      const float4 w1 = *(const float4*)&Ws[c][4];
      num[0] = fmaf(v, w0.x, num[0]); num[1] = fmaf(v, w0.y, num[1]);
      num[2] = fmaf(v, w0.z, num[2]); num[3] = fmaf(v, w0.w, num[3]);
      num[4] = fmaf(v, w1.x, num[4]); num[5] = fmaf(v, w1.y, num[5]);
      num[6] = fmaf(v, w1.z, num[6]); num[7] = fmaf(v, w1.w, num[7]);
    }
    float hn[kL];
#pragma unroll
    for (int l = 0; l < kL; ++l) {
      const float4 a = *(const float4*)&WtWs[l * kL];
      const float4 b = *(const float4*)&WtWs[l * kL + 4];
      float d = kEps;
      d = fmaf(a.x, h[0], d); d = fmaf(a.y, h[1], d);
      d = fmaf(a.z, h[2], d); d = fmaf(a.w, h[3], d);
      d = fmaf(b.x, h[4], d); d = fmaf(b.y, h[5], d);
      d = fmaf(b.z, h[6], d); d = fmaf(b.w, h[7], d);
      hn[l] = h[l] * num[l] / d;
    }
#pragma unroll
    for (int l = 0; l < kL; ++l) { h[l] = hn[l]; Hs[l][tid] = hn[l]; }

    // distributed zeroing of the it+1 buffer: blocks 16..31 each zero one
    // group (576 floats / 256 threads = 2.25 stores/thread). 3-buffer
    // rotation: between consecutive barriers the live buffers are
    // {(it-1)%3 reads, it%3 writes, (it+1)%3 zeroing} — all distinct.
    if ((blockIdx.x >> 4) == 1) {
      float* nb = &ctl->B[(it + 1) % 3][blockIdx.x & (kGroups - 1)][0];
      for (int k = tid; k < kEntries; k += kThreads)
        __hip_atomic_store(&nb[k], 0.0f, __ATOMIC_RELAXED, AGENT);
    }
    __syncthreads();

    // block-local partial VH^T and HH^T over this block's 256 columns
    float* Bg = &ctl->B[it % 3][blockIdx.x & (kGroups - 1)][0];
    {
      const int c0 = tid >> 3, l = tid & 7;
      float a0 = 0.0f, a1 = 0.0f;
      for (int s4 = 0; s4 < kThreads; s4 += 4) {
        const float4 hv = *(const float4*)&Hs[l][s4];
        const float4 v0 = *(const float4*)&Vs[c0][s4];
        const float4 v1 = *(const float4*)&Vs[c0 + 32][s4];
        a0 = fmaf(v0.x, hv.x, a0); a0 = fmaf(v0.y, hv.y, a0);
        a0 = fmaf(v0.z, hv.z, a0); a0 = fmaf(v0.w, hv.w, a0);
        a1 = fmaf(v1.x, hv.x, a1); a1 = fmaf(v1.y, hv.y, a1);
        a1 = fmaf(v1.z, hv.z, a1); a1 = fmaf(v1.w, hv.w, a1);
      }
      __hip_atomic_fetch_add(&Bg[tid], a0, __ATOMIC_RELAXED, AGENT);
      __hip_atomic_fetch_add(&Bg[tid + 256], a1, __ATOMIC_RELAXED, AGENT);
    }
    if (tid < kL * kL) {
      const int j = tid >> 3, l2 = tid & 7;
      float a = 0.0f;
      for (int s4 = 0; s4 < kThreads; s4 += 4) {
        const float4 x = *(const float4*)&Hs[j][s4];
        const float4 y = *(const float4*)&Hs[l2][s4];
        a = fmaf(x.x, y.x, a); a = fmaf(x.y, y.y, a);
        a = fmaf(x.z, y.z, a); a = fmaf(x.w, y.w, a);
      }
      __hip_atomic_fetch_add(&Bg[512 + tid], a, __ATOMIC_RELAXED, AGENT);
    }

    gridbar(ctl, bar_round);

    // finalize 16-group sums (normal loads — fresh after the acquire inv);
    // every block redundantly recomputes W and W^T W
    const float* Bb = &ctl->B[it % 3][0][0];
    if (tid < kL * kL) {
      float sum = 0.0f;
#pragma unroll
      for (int g = 0; g < kGroups; ++g) sum += Bb[g * kEntries + 512 + tid];
      hhts[tid] = sum;
    }
    __syncthreads();
    float wn0, wn1;
    {
      float v0 = 0.0f, v1 = 0.0f;
#pragma unroll
      for (int g = 0; g < kGroups; ++g) {
        v0 += Bb[g * kEntries + tid];
        v1 += Bb[g * kEntries + tid + 256];
      }
      const int c0 = tid >> 3, l0 = tid & 7;
      float d0 = kEps, d1 = kEps;
#pragma unroll
      for (int j = 0; j < kL; ++j) {
        const float hh = hhts[j * kL + l0];
        d0 = fmaf(Ws[c0][j], hh, d0);
        d1 = fmaf(Ws[c0 + 32][j], hh, d1);
      }
      wn0 = Ws[c0][l0] * v0 / d0;
      wn1 = Ws[c0 + 32][l0] * v1 / d1;
    }
    __syncthreads();
    (&Ws[0][0])[tid] = wn0;
    (&Ws[0][0])[tid + 256] = wn1;
    __syncthreads();
    if (tid < kL * kL) {
      const int l = tid >> 3, j = tid & 7;
      float sum = 0.0f;
      for (int c = 0; c < kC; ++c) sum = fmaf(Ws[c][l], Ws[c][j], sum);
      WtWs[tid] = sum;
    }
    __syncthreads();
  }

  // ---------------- epilogue ------------------------------------------------
  // Vhat column + Frobenius error contribution
  float vh[kC];
  float errp = 0.0f;
#pragma unroll
  for (int c = 0; c < kC; ++c) {
    const float4 w0 = *(const float4*)&Ws[c][0];
    const float4 w1 = *(const float4*)&Ws[c][4];
    float t = 0.0f;
    t = fmaf(w0.x, h[0], t); t = fmaf(w0.y, h[1], t);
    t = fmaf(w0.z, h[2], t); t = fmaf(w0.w, h[3], t);
    t = fmaf(w1.x, h[4], t); t = fmaf(w1.y, h[5], t);
    t = fmaf(w1.z, h[6], t); t = fmaf(w1.w, h[7], t);
    vh[c] = t;
    const float d = Vs[c][tid] - t;
    errp = fmaf(d, d, errp);
  }
  {
    float r = errp;
#pragma unroll
    for (int off = 32; off > 0; off >>= 1) r += __shfl_down(r, off, 64);
    __syncthreads();
    if ((tid & 63) == 0) reds[tid >> 6] = r;
    __syncthreads();
    if (tid == 0)
      __hip_atomic_fetch_add(&ctl->err_sum, reds[0] + reds[1] + reds[2] + reds[3],
                             __ATOMIC_RELAXED, AGENT);
  }
  // eps_hat = w_post2 . relu(w_post1 . vh), streamed so only vh+outacc live
  float outacc[kC];
#pragma unroll
  for (int o = 0; o < kC; ++o) outacc[o] = 0.0f;
  for (int o = 0; o < kC; ++o) {
    float t = 0.0f;
#pragma unroll
    for (int c = 0; c < kC; ++c) t = fmaf(w_post1[o * kC + c], vh[c], t);
    t = fmaxf(t, 0.0f);
#pragma unroll
    for (int o2 = 0; o2 < kC; ++o2)
      outacc[o2] = fmaf(w_post2[o2 * kC + o], t, outacc[o2]);
  }
#pragma unroll
  for (int o = 0; o < kC; ++o) out[o * kS + s] = outacc[o];

  gridbar(ctl, bar_round);
  if (blockIdx.x == 0 && tid == 0)
    out[kC * kS] = sqrtf(__hip_atomic_load(&ctl->err_sum, __ATOMIC_RELAXED, AGENT));
}

extern "C" void kernel_launch(void* const* d_in, const int* in_sizes, int n_in,
                              void* d_out, int out_size, void* d_ws, size_t ws_size,
                              hipStream_t stream) {
  (void)in_sizes; (void)n_in; (void)out_size; (void)ws_size;
  const float* eps     = (const float*)d_in[0];
  const float* w_pre   = (const float*)d_in[1];
  const float* b_pre   = (const float*)d_in[2];
  const float* w_post1 = (const float*)d_in[3];
  const float* w_post2 = (const float*)d_in[4];
  float* out = (float*)d_out;
  Ctl* ctl = (Ctl*)d_ws;

  init_ctl<<<64, 256, 0, stream>>>((unsigned*)d_ws);
  fsam_nmf<<<kBlocks, kThreads, 0, stream>>>(eps, w_pre, b_pre, w_post1,
                                             w_post2, out, ctl);
}

// Round 3
// 741.313 us; speedup vs baseline: 3.5427x; 1.2384x over previous
//
#include <hip/hip_runtime.h>
#include <stdint.h>

// 1 = JAX >= 0.5 default (jax_threefry_partitionable=True); 0 = legacy scheme.
#define JAX_PARTITIONABLE 1

constexpr int kC = 64;          // channels (= NMF rows T)
constexpr int kS = 65536;       // spatial 16*64*64 (= NMF cols M)
constexpr int kL = 8;           // NMF rank
constexpr int kIters = 50;
constexpr int kBlocks = 256;
constexpr int kThreads = 512;   // 8 waves/block, 1 block/CU -> 2 waves/SIMD
constexpr int kCols = 256;      // columns per block
constexpr int kGroups = 16;     // stage-1 reduction groups (16 blocks/group)
constexpr int kEntries = 576;   // 512 (VH^T) + 64 (HH^T)
constexpr float kEps = 1.1920929e-07f;

#define AGENT __HIP_MEMORY_SCOPE_AGENT

struct Ctl {
  unsigned root;  unsigned pad0[31];     // barrier root counter
  unsigned leaf[16][32];                 // leaf counters, 128 B apart
  float mean_sum; float err_sum; float pad1[30];
  float B[3][kGroups][kEntries];         // rotating accumulator buffers
};

__device__ __forceinline__ uint2 tf2x32(unsigned k0, unsigned k1,
                                        unsigned x0, unsigned x1) {
  unsigned k2 = k0 ^ k1 ^ 0x1BD11BDAu;
  x0 += k0; x1 += k1;
#define TF_RND(r) { x0 += x1; x1 = (x1 << (r)) | (x1 >> (32 - (r))); x1 ^= x0; }
  TF_RND(13) TF_RND(15) TF_RND(26) TF_RND(6)
  x0 += k1; x1 += k2 + 1u;
  TF_RND(17) TF_RND(29) TF_RND(16) TF_RND(24)
  x0 += k2; x1 += k0 + 2u;
  TF_RND(13) TF_RND(15) TF_RND(26) TF_RND(6)
  x0 += k0; x1 += k1 + 3u;
  TF_RND(17) TF_RND(29) TF_RND(16) TF_RND(24)
  x0 += k1; x1 += k2 + 4u;
  TF_RND(13) TF_RND(15) TF_RND(26) TF_RND(6)
  x0 += k2; x1 += k0 + 5u;
#undef TF_RND
  return make_uint2(x0, x1);
}

__device__ __forceinline__ float u01(unsigned b) {
  return __uint_as_float((b >> 9) | 0x3f800000u) - 1.0f;
}

// Two-level monotonic grid barrier: 16 leaves x 16 arrivals, then 16 root
// arrivals. Avoids 256 serialized same-address RMWs. Data safety: the
// __syncthreads before arrival drains vmcnt (all sc1 data ops at L3); the
// acquire fence after the spin invalidates L1/L2 so normal loads refetch.
__device__ __forceinline__ void gridbar(Ctl* ctl, unsigned& round) {
  ++round;
  __syncthreads();
  if (threadIdx.x == 0) {
    const unsigned target = round * 16u;
    const unsigned leaf = blockIdx.x & 15u;
    unsigned a = __hip_atomic_fetch_add(&ctl->leaf[leaf][0], 1u,
                                        __ATOMIC_RELAXED, AGENT);
    if (a == target - 1u)   // last of this leaf's 16 blocks this round
      __hip_atomic_fetch_add(&ctl->root, 1u, __ATOMIC_RELAXED, AGENT);
    while (__hip_atomic_load(&ctl->root, __ATOMIC_RELAXED, AGENT) < target)
      __builtin_amdgcn_s_sleep(1);
    __builtin_amdgcn_fence(__ATOMIC_ACQUIRE, "agent");
  }
  __syncthreads();
}

__global__ void init_ctl(unsigned* ws) {
  const unsigned n = (unsigned)(sizeof(Ctl) / 4);
  for (unsigned i = blockIdx.x * blockDim.x + threadIdx.x; i < n;
       i += gridDim.x * blockDim.x)
    ws[i] = 0u;
}

__global__ __launch_bounds__(kThreads, 2) void fsam_nmf(
    const float* __restrict__ eps, const float* __restrict__ w_pre,
    const float* __restrict__ b_pre, const float* __restrict__ w_post1,
    const float* __restrict__ w_post2, float* __restrict__ out, Ctl* ctl) {
  // stride 260 (== 4 mod 32): conflict-free stride-1 rows, 16B-aligned rows.
  __shared__ __align__(16) float Vs[kC][260];
  __shared__ __align__(16) float Hs[kL][260];
  __shared__ __align__(16) float Pn[kL][260];      // q=1 H-update partials
  __shared__ __align__(16) float Pv[4][512];       // VH^T tile partials
  __shared__ __align__(16) float Ph[16][64];       // HH^T tile partials
  __shared__ __align__(16) float Ws[kC][kL];
  __shared__ __align__(16) float WtWs[kL * kL];
  __shared__ __align__(16) float hhts[kL * kL];
  __shared__ float reds[8];

  const int tid = threadIdx.x;
  const int t = tid & 255;        // column within block
  const int q = tid >> 8;         // channel-half 0/1
  const int obase = q * 32;
  const int s = blockIdx.x * kCols + t;   // global spatial column
  unsigned bar_round = 0;

  // ---------------- phase 0: V column = relu(W_pre . eps_col + b) ----------
  // thread (q,t) computes output channels [32q, 32q+32) of column t.
  float acc[32];
#pragma unroll
  for (int o = 0; o < 32; ++o) acc[o] = b_pre[obase + o];
  for (int c = 0; c < kC; ++c) {
    const float e = eps[c * kS + s];
#pragma unroll
    for (int o = 0; o < 32; ++o)
      acc[o] = fmaf(w_pre[(obase + o) * kC + c], e, acc[o]);
  }
  float lsum = 0.0f;
#pragma unroll
  for (int o = 0; o < 32; ++o) {
    acc[o] = fmaxf(acc[o], 0.0f);
    Vs[obase + o][t] = acc[o];
    lsum += acc[o];
  }
  {
    float r = lsum;
#pragma unroll
    for (int off = 32; off > 0; off >>= 1) r += __shfl_down(r, off, 64);
    if ((tid & 63) == 0) reds[tid >> 6] = r;
    __syncthreads();
    if (tid == 0) {
      float sm = 0.0f;
#pragma unroll
      for (int w = 0; w < 8; ++w) sm += reds[w];
      __hip_atomic_fetch_add(&ctl->mean_sum, sm, __ATOMIC_RELAXED, AGENT);
    }
  }
  gridbar(ctl, bar_round);
  const float avg = sqrtf(
      __hip_atomic_load(&ctl->mean_sum, __ATOMIC_RELAXED, AGENT) *
      (1.0f / (4194304.0f * 8.0f)));

  // ---------------- threefry init (JAX-exact) -------------------------------
#if JAX_PARTITIONABLE
  const uint2 kw = tf2x32(0u, 0u, 0u, 0u);
  const uint2 kh = tf2x32(0u, 0u, 0u, 1u);
#else
  const uint2 A0 = tf2x32(0u, 0u, 0u, 2u);
  const uint2 A1 = tf2x32(0u, 0u, 1u, 3u);
  const uint2 kw = make_uint2(A0.x, A1.x);
  const uint2 kh = make_uint2(A0.y, A1.y);
#endif

  float h[kL] = {0, 0, 0, 0, 0, 0, 0, 0};   // live only in q==0 threads
  if (q == 0) {
#if JAX_PARTITIONABLE
#pragma unroll
    for (int l = 0; l < kL; ++l) {
      uint2 r = tf2x32(kh.x, kh.y, 0u, (unsigned)(l * kS + s));
      h[l] = avg * u01(r.x ^ r.y);
    }
#else
#pragma unroll
    for (int l = 0; l < 4; ++l) {
      unsigned i = (unsigned)(l * kS + s);
      uint2 r = tf2x32(kh.x, kh.y, i, i + 262144u);
      h[l] = avg * u01(r.x);
      h[l + 4] = avg * u01(r.y);
    }
#endif
  }
  // W0: 512 flat entries, one per thread
  {
#if JAX_PARTITIONABLE
    uint2 r0 = tf2x32(kw.x, kw.y, 0u, (unsigned)tid);
    (&Ws[0][0])[tid] = avg * u01(r0.x ^ r0.y);
#else
    if (tid < 256) {
      uint2 r = tf2x32(kw.x, kw.y, (unsigned)tid, (unsigned)(tid + 256));
      (&Ws[0][0])[tid] = avg * u01(r.x);
      (&Ws[0][0])[tid + 256] = avg * u01(r.y);
    }
#endif
  }
  __syncthreads();
  if (tid < kL * kL) {
    const int l = tid >> 3, j = tid & 7;
    float sum = 0.0f;
    for (int c = 0; c < kC; ++c) sum = fmaf(Ws[c][l], Ws[c][j], sum);
    WtWs[tid] = sum;
  }
  __syncthreads();

  // ---------------- 50 MU iterations, one grid barrier each -----------------
  for (int it = 0; it < kIters; ++it) {
    // H-update numerator partial over this thread's channel half
    float num[kL] = {0, 0, 0, 0, 0, 0, 0, 0};
    for (int ci = 0; ci < 32; ++ci) {
      const int c = obase + ci;
      const float v = Vs[c][t];
      const float4 w0 = *(const float4*)&Ws[c][0];
      const float4 w1 = *(const float4*)&Ws[c][4];
      num[0] = fmaf(v, w0.x, num[0]); num[1] = fmaf(v, w0.y, num[1]);
      num[2] = fmaf(v, w0.z, num[2]); num[3] = fmaf(v, w0.w, num[3]);
      num[4] = fmaf(v, w1.x, num[4]); num[5] = fmaf(v, w1.y, num[5]);
      num[6] = fmaf(v, w1.z, num[6]); num[7] = fmaf(v, w1.w, num[7]);
    }
    if (q == 1) {
#pragma unroll
      for (int l = 0; l < kL; ++l) Pn[l][t] = num[l];
    }
    __syncthreads();
    if (q == 0) {
      float hn[kL];
#pragma unroll
      for (int l = 0; l < kL; ++l) {
        const float4 a = *(const float4*)&WtWs[l * kL];
        const float4 b = *(const float4*)&WtWs[l * kL + 4];
        float d = kEps;
        d = fmaf(a.x, h[0], d); d = fmaf(a.y, h[1], d);
        d = fmaf(a.z, h[2], d); d = fmaf(a.w, h[3], d);
        d = fmaf(b.x, h[4], d); d = fmaf(b.y, h[5], d);
        d = fmaf(b.z, h[6], d); d = fmaf(b.w, h[7], d);
        hn[l] = h[l] * (num[l] + Pn[l][t]) / d;
      }
#pragma unroll
      for (int l = 0; l < kL; ++l) { h[l] = hn[l]; Hs[l][t] = hn[l]; }
    } else if ((blockIdx.x >> 4) == 1) {
      // q=1 threads are idle here: blocks 16..31 zero the it+1 buffer.
      // 3-buffer rotation keeps {reads (it-1)%3, writes it%3, zero (it+1)%3}
      // distinct between consecutive barriers.
      float* nb = &ctl->B[(it + 1) % 3][blockIdx.x & 15][0];
      for (int k = t; k < kEntries; k += 256)
        __hip_atomic_store(&nb[k], 0.0f, __ATOMIC_RELAXED, AGENT);
    }
    __syncthreads();

    // VH^T partials: 128 tiles (2c x 2l) x 4 column-ranges of 64
    {
      const int range = tid >> 7;         // 0..3
      const int tile = tid & 127;         // 0..127
      const int c0 = (tile >> 2) * 2;     // 0,2,..62
      const int l0 = (tile & 3) * 2;      // 0,2,4,6
      const int sbeg = range * 64;
      float a00 = 0, a01 = 0, a10 = 0, a11 = 0;
      for (int s4 = sbeg; s4 < sbeg + 64; s4 += 4) {
        const float4 h0 = *(const float4*)&Hs[l0][s4];
        const float4 h1 = *(const float4*)&Hs[l0 + 1][s4];
        const float4 v0 = *(const float4*)&Vs[c0][s4];
        const float4 v1 = *(const float4*)&Vs[c0 + 1][s4];
        a00 = fmaf(v0.x, h0.x, a00); a00 = fmaf(v0.y, h0.y, a00);
        a00 = fmaf(v0.z, h0.z, a00); a00 = fmaf(v0.w, h0.w, a00);
        a01 = fmaf(v0.x, h1.x, a01); a01 = fmaf(v0.y, h1.y, a01);
        a01 = fmaf(v0.z, h1.z, a01); a01 = fmaf(v0.w, h1.w, a01);
        a10 = fmaf(v1.x, h0.x, a10); a10 = fmaf(v1.y, h0.y, a10);
        a10 = fmaf(v1.z, h0.z, a10); a10 = fmaf(v1.w, h0.w, a10);
        a11 = fmaf(v1.x, h1.x, a11); a11 = fmaf(v1.y, h1.y, a11);
        a11 = fmaf(v1.z, h1.z, a11); a11 = fmaf(v1.w, h1.w, a11);
      }
      Pv[range][c0 * 8 + l0] = a00;
      Pv[range][c0 * 8 + l0 + 1] = a01;
      Pv[range][(c0 + 1) * 8 + l0] = a10;
      Pv[range][(c0 + 1) * 8 + l0 + 1] = a11;
    }
    // HH^T partials: 16 tiles (2j x 2l) x 16 column-ranges of 16, threads 0..255
    if (tid < 256) {
      const int tile = tid >> 4, range = tid & 15;
      const int j0 = (tile >> 2) * 2, l0 = (tile & 3) * 2;
      const int sbeg = range * 16;
      float a00 = 0, a01 = 0, a10 = 0, a11 = 0;
      for (int s4 = sbeg; s4 < sbeg + 16; s4 += 4) {
        const float4 x0 = *(const float4*)&Hs[j0][s4];
        const float4 x1 = *(const float4*)&Hs[j0 + 1][s4];
        const float4 y0 = *(const float4*)&Hs[l0][s4];
        const float4 y1 = *(const float4*)&Hs[l0 + 1][s4];
        a00 = fmaf(x0.x, y0.x, a00); a00 = fmaf(x0.y, y0.y, a00);
        a00 = fmaf(x0.z, y0.z, a00); a00 = fmaf(x0.w, y0.w, a00);
        a01 = fmaf(x0.x, y1.x, a01); a01 = fmaf(x0.y, y1.y, a01);
        a01 = fmaf(x0.z, y1.z, a01); a01 = fmaf(x0.w, y1.w, a01);
        a10 = fmaf(x1.x, y0.x, a10); a10 = fmaf(x1.y, y0.y, a10);
        a10 = fmaf(x1.z, y0.z, a10); a10 = fmaf(x1.w, y0.w, a10);
        a11 = fmaf(x1.x, y1.x, a11); a11 = fmaf(x1.y, y1.y, a11);
        a11 = fmaf(x1.z, y1.z, a11); a11 = fmaf(x1.w, y1.w, a11);
      }
      Ph[range][j0 * 8 + l0] = a00;
      Ph[range][j0 * 8 + l0 + 1] = a01;
      Ph[range][(j0 + 1) * 8 + l0] = a10;
      Ph[range][(j0 + 1) * 8 + l0 + 1] = a11;
    }
    __syncthreads();

    // combine partials in LDS, then ONE atomic per entry (16-way contention)
    float* Bg = &ctl->B[it % 3][blockIdx.x & 15][0];
    {
      const float v = Pv[0][tid & 511] + Pv[1][tid & 511] +
                      Pv[2][tid & 511] + Pv[3][tid & 511];
      __hip_atomic_fetch_add(&Bg[tid], v, __ATOMIC_RELAXED, AGENT);
    }
    if (tid >= 448) {
      const int e = tid - 448;
      float v = 0.0f;
#pragma unroll
      for (int r = 0; r < 16; ++r) v += Ph[r][e];
      __hip_atomic_fetch_add(&Bg[512 + e], v, __ATOMIC_RELAXED, AGENT);
    }

    gridbar(ctl, bar_round);

    // finalize: issue the group-sum global loads FIRST (no sync in the way)
    const float* Bb = &ctl->B[it % 3][0][0];
    float v = 0.0f;
    {
#pragma unroll
      for (int g = 0; g < kGroups; ++g) v += Bb[g * kEntries + tid];
    }
    if (tid < kL * kL) {
      float sum = 0.0f;
#pragma unroll
      for (int g = 0; g < kGroups; ++g) sum += Bb[g * kEntries + 512 + tid];
      hhts[tid] = sum;
    }
    __syncthreads();
    float wn;
    {
      const int c0 = tid >> 3, l0 = tid & 7;
      float d = kEps;
#pragma unroll
      for (int j = 0; j < kL; ++j) d = fmaf(Ws[c0][j], hhts[j * kL + l0], d);
      wn = (&Ws[0][0])[tid] * v / d;
    }
    __syncthreads();
    (&Ws[0][0])[tid] = wn;
    __syncthreads();
    if (tid < kL * kL) {
      const int l = tid >> 3, j = tid & 7;
      float sum = 0.0f;
      for (int c = 0; c < kC; ++c) sum = fmaf(Ws[c][l], Ws[c][j], sum);
      WtWs[tid] = sum;
    }
    __syncthreads();
  }

  // ---------------- epilogue ------------------------------------------------
  if (q == 1) {
#pragma unroll
    for (int l = 0; l < kL; ++l) h[l] = Hs[l][t];
  }
  // vh for own channel half; Frobenius partial; overwrite Vs with vh in place
  float errp = 0.0f;
  for (int ci = 0; ci < 32; ++ci) {
    const int c = obase + ci;
    const float4 w0 = *(const float4*)&Ws[c][0];
    const float4 w1 = *(const float4*)&Ws[c][4];
    float tcc = 0.0f;
    tcc = fmaf(w0.x, h[0], tcc); tcc = fmaf(w0.y, h[1], tcc);
    tcc = fmaf(w0.z, h[2], tcc); tcc = fmaf(w0.w, h[3], tcc);
    tcc = fmaf(w1.x, h[4], tcc); tcc = fmaf(w1.y, h[5], tcc);
    tcc = fmaf(w1.z, h[6], tcc); tcc = fmaf(w1.w, h[7], tcc);
    const float d = Vs[c][t] - tcc;
    errp = fmaf(d, d, errp);
    Vs[c][t] = tcc;               // same thread read+write: no hazard
  }
  {
    float r = errp;
#pragma unroll
    for (int off = 32; off > 0; off >>= 1) r += __shfl_down(r, off, 64);
    __syncthreads();
    if ((tid & 63) == 0) reds[tid >> 6] = r;
    __syncthreads();
    if (tid == 0) {
      float sm = 0.0f;
#pragma unroll
      for (int w = 0; w < 8; ++w) sm += reds[w];
      __hip_atomic_fetch_add(&ctl->err_sum, sm, __ATOMIC_RELAXED, AGENT);
    }
  }
  __syncthreads();   // all vh written before y reads full columns
  // y = relu(W1 . vh): own 32 outputs, full 64-channel input from Vs
  float yacc[32];
#pragma unroll
  for (int o = 0; o < 32; ++o) yacc[o] = 0.0f;
  for (int c = 0; c < kC; ++c) {
    const float vv = Vs[c][t];
#pragma unroll
    for (int o = 0; o < 32; ++o)
      yacc[o] = fmaf(w_post1[(obase + o) * kC + c], vv, yacc[o]);
  }
  __syncthreads();   // all vh reads done before overwrite with y
#pragma unroll
  for (int o = 0; o < 32; ++o) Vs[obase + o][t] = fmaxf(yacc[o], 0.0f);
  __syncthreads();
  // eps_hat = W2 . y: own 32 outputs, full y column from Vs
  float outacc[32];
#pragma unroll
  for (int o = 0; o < 32; ++o) outacc[o] = 0.0f;
  for (int c = 0; c < kC; ++c) {
    const float yv = Vs[c][t];
#pragma unroll
    for (int o = 0; o < 32; ++o)
      outacc[o] = fmaf(w_post2[(obase + o) * kC + c], yv, outacc[o]);
  }
#pragma unroll
  for (int o = 0; o < 32; ++o) out[(obase + o) * kS + s] = outacc[o];

  gridbar(ctl, bar_round);
  if (blockIdx.x == 0 && tid == 0)
    out[kC * kS] = sqrtf(__hip_atomic_load(&ctl->err_sum, __ATOMIC_RELAXED, AGENT));
}

extern "C" void kernel_launch(void* const* d_in, const int* in_sizes, int n_in,
                              void* d_out, int out_size, void* d_ws, size_t ws_size,
                              hipStream_t stream) {
  (void)in_sizes; (void)n_in; (void)out_size; (void)ws_size;
  const float* eps     = (const float*)d_in[0];
  const float* w_pre   = (const float*)d_in[1];
  const float* b_pre   = (const float*)d_in[2];
  const float* w_post1 = (const float*)d_in[3];
  const float* w_post2 = (const float*)d_in[4];
  float* out = (float*)d_out;
  Ctl* ctl = (Ctl*)d_ws;

  init_ctl<<<64, 256, 0, stream>>>((unsigned*)d_ws);
  fsam_nmf<<<kBlocks, kThreads, 0, stream>>>(eps, w_pre, b_pre, w_post1,
                                             w_post2, out, ctl);
}